// Round 17
// baseline (91.614 us; speedup 1.0000x reference)
//
#include <hip/hip_runtime.h>
#include <math.h>

#define NH 4
#define EDIM 32
#define NEG_SLOPE 0.2f
#define BSH 5                  // bucket = col>>5 (32 nodes per bucket)

typedef __attribute__((ext_vector_type(8))) short short8;
typedef __attribute__((ext_vector_type(4))) float f32x4;
typedef __attribute__((ext_vector_type(2))) float f32x2;

__device__ __forceinline__ unsigned short f2bf(float f) {
    unsigned int x = __builtin_bit_cast(unsigned int, f);
    unsigned int r = (x + 0x7fffu + ((x >> 16) & 1u)) >> 16;
    return (unsigned short)r;
}
__device__ __forceinline__ float bf2f(unsigned short u) {
    unsigned int x = ((unsigned int)u) << 16;
    return __builtin_bit_cast(float, x);
}

// ---------------------------------------------------------------------------
// Prep: blocks [0,64): weight transpose+bf16.
//       blocks [64,64+T): h_e_t for one edge type each.
__global__ __launch_bounds__(256) void k_prep(
    const float* __restrict__ W, const float* __restrict__ Rw,
    unsigned short* __restrict__ Wt, unsigned short* __restrict__ Rwt,
    const float* __restrict__ edge_emb, const float* __restrict__ W_r,
    const float* __restrict__ a_e, float* __restrict__ h_e_t)
{
    int tid = threadIdx.x;
    if (blockIdx.x < 64) {
        int idx = blockIdx.x * 256 + tid;       // 0..16383
        int n = idx >> 7, k = idx & 127;
        Wt[n * 128 + k]  = f2bf(W[k * 128 + n]);
        Rwt[n * 128 + k] = f2bf(Rw[k * 128 + n]);
        return;
    }
    int t = blockIdx.x - 64;
    if (tid < 128) {
        int rem = tid;                          // h*32+k
        float v = 0.f;
#pragma unroll
        for (int e = 0; e < EDIM; ++e)
            v += edge_emb[t * EDIM + e] * W_r[(size_t)(t * EDIM + e) * 128 + rem];
        v *= a_e[rem];
#pragma unroll
        for (int off = 16; off >= 1; off >>= 1)
            v += __shfl_xor(v, off);
        if ((rem & 31) == 0) h_e_t[t * NH + (rem >> 5)] = v;
    }
}

// ---------------------------------------------------------------------------
// Merged: blocks [0,nFill): block-local counting sort of 8192 edges by bucket
//   into the block's OWN contiguous 32KB run of ebuf (writes fully coalesced /
//   L2-merged; no global atomics).  meta[fb*NB+bk] = localOffs<<8 | count.
// blocks [nFill,..): MFMA GEMM with 32KB LDS (A + half-B staging).
__global__ __launch_bounds__(256) void k_gemm_fill(
    const float* __restrict__ A, const unsigned short* __restrict__ Wt,
    const unsigned short* __restrict__ Rwt, const float* __restrict__ Rb,
    const float* __restrict__ a_l, const float* __restrict__ a_r,
    unsigned short* __restrict__ EmbBf, unsigned short* __restrict__ ResBf,
    float* __restrict__ h_l, float* __restrict__ h_r, int M,
    const int* __restrict__ row, const int* __restrict__ col,
    const int* __restrict__ etype, unsigned* __restrict__ meta,
    unsigned* __restrict__ ebuf, int E, int NB, int nFill)
{
    __shared__ char lds[32768];                 // fill: bins[2048]+wtot ; gemm: A+B
    int tid = threadIdx.x;

    if ((int)blockIdx.x < nFill) {
        int* bins = (int*)lds;                  // 2048 ints (>= NB)
        int* wtot = bins + 2048;                // 4 ints
        for (int i = tid; i < 2048; i += 256) bins[i] = 0;
        __syncthreads();
        int fb = blockIdx.x;
        int lo = fb * 8192;
        int hi = lo + 8192 < E ? lo + 8192 : E;
        // pass 1: histogram
        for (int i = lo + tid; i < hi; i += 256)
            atomicAdd(&bins[col[i] >> BSH], 1);
        __syncthreads();
        // block-local exclusive scan over 2048 bins (8 bins / thread)
        int c[8];
        int S = 0;
#pragma unroll
        for (int u = 0; u < 8; ++u) { c[u] = bins[tid * 8 + u]; S += c[u]; }
        int w_ = tid >> 6, lane_ = tid & 63;
        int s = S;
#pragma unroll
        for (int off = 1; off < 64; off <<= 1) {
            int y = __shfl_up(s, off);
            if (lane_ >= off) s += y;
        }
        if (lane_ == 63) wtot[w_] = s;
        __syncthreads();
        int base = s - S;
        for (int ww = 0; ww < w_; ++ww) base += wtot[ww];
        __syncthreads();                        // bins reads done before overwrite
#pragma unroll
        for (int u = 0; u < 8; ++u) {
            int bk = tid * 8 + u;
            bins[bk] = base;                    // start offset -> cursor
            if (bk < NB) {
                int cc = c[u] < 255 ? c[u] : 255;
                meta[(size_t)fb * NB + bk] = (unsigned)((base << 8) | cc);
            }
            base += c[u];
        }
        __syncthreads();
        // pass 2: scatter into this block's contiguous run [lo, lo+8192)
        for (int i = lo + tid; i < hi; i += 256) {
            int cc = col[i];
            int bk = cc >> BSH;
            int p = atomicAdd(&bins[bk], 1);
            ebuf[lo + p] = (unsigned)row[i] | ((unsigned)etype[i] << 16)
                         | ((unsigned)(cc & 31) << 24);
        }
        return;
    }

    // ---- MFMA GEMM ----
    int m0 = ((int)blockIdx.x - nFill) * 64;
#pragma unroll
    for (int i = 0; i < 4; ++i) {
        int c = tid + 256 * i;                  // 0..1023
        int r = c >> 4, kc = c & 15;
        int grow = m0 + r;
        float4 v0 = make_float4(0.f, 0.f, 0.f, 0.f), v1 = v0;
        if (grow < M) {
            v0 = *(const float4*)&A[(size_t)grow * 128 + kc * 8];
            v1 = *(const float4*)&A[(size_t)grow * 128 + kc * 8 + 4];
        }
        union { unsigned short u[8]; uint4 v; } p;
        p.u[0] = f2bf(v0.x); p.u[1] = f2bf(v0.y); p.u[2] = f2bf(v0.z); p.u[3] = f2bf(v0.w);
        p.u[4] = f2bf(v1.x); p.u[5] = f2bf(v1.y); p.u[6] = f2bf(v1.z); p.u[7] = f2bf(v1.w);
        int b = (r * 256 + kc * 16) ^ ((r & 7) << 4);
        *(uint4*)&lds[b] = p.v;
    }

    int w = tid >> 6, lane = tid & 63;
    int g = lane >> 4, l15 = lane & 15;
    int lrow = w * 16 + l15;

    auto stageB = [&](const unsigned short* src) {
#pragma unroll
        for (int i = 0; i < 4; ++i) {
            int c = tid + 256 * i;              // 0..1023
            int n2 = c >> 4, kc = c & 15;
            uint4 v = *(const uint4*)&src[n2 * 128 + kc * 8];
            int b = 16384 + ((n2 * 256 + kc * 16) ^ ((n2 & 7) << 4));
            *(uint4*)&lds[b] = v;
        }
    };
    auto computeHalf = [&](f32x4* accp, const short8* a) {
#pragma unroll
        for (int f = 0; f < 4; ++f) {
            int n2 = f * 16 + l15;
            int nsw = (n2 & 7) << 4;
#pragma unroll
            for (int s = 0; s < 4; ++s) {
                short8 b = *(const short8*)&lds[16384 + ((n2 * 256 + s * 64 + g * 16) ^ nsw)];
                accp[f] = __builtin_amdgcn_mfma_f32_16x16x32_bf16(a[s], b, accp[f], 0, 0, 0);
            }
        }
    };

    stageB(Wt);
    __syncthreads();

    short8 a[4];
#pragma unroll
    for (int s = 0; s < 4; ++s)
        a[s] = *(const short8*)&lds[(lrow * 256 + s * 64 + g * 16) ^ ((lrow & 7) << 4)];

    f32x4 acc[8];
#pragma unroll
    for (int f = 0; f < 8; ++f) acc[f] = (f32x4){0.f, 0.f, 0.f, 0.f};

    computeHalf(&acc[0], a);                    // cols 0..63
    __syncthreads();
    stageB(Wt + 64 * 128);
    __syncthreads();
    computeHalf(&acc[4], a);                    // cols 64..127

#pragma unroll
    for (int f = 0; f < 8; ++f) {
        int col2 = f * 16 + l15;
#pragma unroll
        for (int reg = 0; reg < 4; ++reg) {
            int grow = m0 + w * 16 + g * 4 + reg;
            if (grow < M) EmbBf[(size_t)grow * 128 + col2] = f2bf(acc[f][reg]);
        }
    }
    {
        float alv[8], arv[8];
#pragma unroll
        for (int f = 0; f < 8; ++f) {
            alv[f] = a_l[f * 16 + l15];
            arv[f] = a_r[f * 16 + l15];
        }
#pragma unroll
        for (int reg = 0; reg < 4; ++reg) {
            float4 hl4, hr4;
#pragma unroll
            for (int hh = 0; hh < 4; ++hh) {
                float pl = alv[2 * hh] * acc[2 * hh][reg] + alv[2 * hh + 1] * acc[2 * hh + 1][reg];
                float pr = arv[2 * hh] * acc[2 * hh][reg] + arv[2 * hh + 1] * acc[2 * hh + 1][reg];
#pragma unroll
                for (int off = 8; off >= 1; off >>= 1) {
                    pl += __shfl_xor(pl, off);
                    pr += __shfl_xor(pr, off);
                }
                (&hl4.x)[hh] = pl;
                (&hr4.x)[hh] = pr;
            }
            int grow = m0 + w * 16 + g * 4 + reg;
            if (l15 == 0 && grow < M) {
                *(float4*)&h_l[(size_t)grow * 4] = hl4;
                *(float4*)&h_r[(size_t)grow * 4] = hr4;
            }
        }
    }

    // ---- res pass ----
    __syncthreads();
    stageB(Rwt);
    __syncthreads();
#pragma unroll
    for (int f = 0; f < 8; ++f) acc[f] = (f32x4){0.f, 0.f, 0.f, 0.f};
    computeHalf(&acc[0], a);
    __syncthreads();
    stageB(Rwt + 64 * 128);
    __syncthreads();
    computeHalf(&acc[4], a);

#pragma unroll
    for (int f = 0; f < 8; ++f) {
        int col2 = f * 16 + l15;
        float bias = Rb[col2];
#pragma unroll
        for (int reg = 0; reg < 4; ++reg) {
            int grow = m0 + w * 16 + g * 4 + reg;
            if (grow < M) ResBf[(size_t)grow * 128 + col2] = f2bf(acc[f][reg] + bias);
        }
    }
}

// ---------------------------------------------------------------------------
// Fused chunk-merge + within-bucket sort + aggregate.  512 threads per
// 32-node bucket.  Chunk ch of bucket b lives at ebuf[ch*8192 + (meta>>8)],
// count = meta&255.  Wave-0 shuffle scan, thread-per-slot dense copy + sparse
// tail, histogram fused; then scatter to sedge and the r14 aggregate core.
__global__ __launch_bounds__(512) void k_sort_aggregate(
    const unsigned* __restrict__ ebuf, const unsigned* __restrict__ meta,
    int nF, int NB,
    const float* __restrict__ h_l, const float* __restrict__ h_e_t,
    const float* __restrict__ h_r, const unsigned short* __restrict__ embBf,
    const unsigned short* __restrict__ resBf, float* __restrict__ out, int N)
{
    __shared__ int stage[1024];
    __shared__ int sedge[1024];
    __shared__ int chcnt[128];
    __shared__ int chbase[128];
    __shared__ int choff[132];
    __shared__ int cnt32[32];
    __shared__ int scn32[33];
    __shared__ char shalpha[8 * 1536];

    int b = blockIdx.x;
    int tid = threadIdx.x;
    int w = tid >> 6, lane = tid & 63;

    // ---- wave-0 chunk-meta load + shuffle scan (2 chunks per lane) ----
    if (tid < 32) cnt32[tid] = 0;
    if (tid < 64) {
        int i0 = tid * 2, i1 = i0 + 1;
        unsigned m0v = (i0 < nF) ? meta[(size_t)i0 * NB + b] : 0u;
        unsigned m1v = (i1 < nF) ? meta[(size_t)i1 * NB + b] : 0u;
        int c0 = (int)(m0v & 255u), c1 = (int)(m1v & 255u);
        chcnt[i0] = c0; chcnt[i1] = c1;
        chbase[i0] = (int)(m0v >> 8); chbase[i1] = (int)(m1v >> 8);
        int s = c0 + c1;
#pragma unroll
        for (int off = 1; off < 64; off <<= 1) {
            int u2 = __shfl_up(s, off);
            if (tid >= off) s += u2;
        }
        choff[i0] = s - c1 - c0;
        choff[i1] = s - c1;
        if (tid == 63) choff[128] = s;
    }
    __syncthreads();
    int m = choff[128];

    // ---- pass A: slots 0..7, 8 threads per chunk, 2 iters cover 128 chunks
#pragma unroll
    for (int itc = 0; itc < 2; ++itc) {
        int ch = itc * 64 + (tid >> 3);
        int sl = tid & 7;
        int c = chcnt[ch];
        if (sl < c) {
            int v = (int)ebuf[ch * 8192 + chbase[ch] + sl];
            stage[choff[ch] + sl] = v;
            atomicAdd(&cnt32[(v >> 24) & 31], 1);
        }
    }
    // ---- pass B: rare chunks with c>8, wave per chunk ----
    for (int ch = w; ch < 128; ch += 8) {
        int c = chcnt[ch];
        if (c > 8 && lane < c - 8) {
            int v = (int)ebuf[ch * 8192 + chbase[ch] + 8 + lane];
            stage[choff[ch] + 8 + lane] = v;
            atomicAdd(&cnt32[(v >> 24) & 31], 1);
        }
    }
    __syncthreads();

    // ---- node scan + scatter to sedge ----
    if (tid < 32) {
        int v = cnt32[tid];
        int s = v;
#pragma unroll
        for (int off = 1; off < 32; off <<= 1) {
            int u2 = __shfl_up(s, off);
            if (tid >= off) s += u2;
        }
        scn32[tid + 1] = s;
        if (tid == 0) scn32[0] = 0;
        cnt32[tid] = s - v;                     // exclusive; reuse as cursor
    }
    __syncthreads();
    for (int i = tid; i < m; i += 512) {
        int e = stage[i];
        int p = atomicAdd(&cnt32[(e >> 24) & 31], 1);
        sedge[p] = e & 0x00FFFFFF;
    }
    __syncthreads();

    int myh = lane >> 4;                        // parking/fallback head
    int l31 = lane & 31;
    int sel = lane >> 5;                        // which edge of the pair
    int hq = l31 >> 3;                          // gather head (elements l31*4..+3)
    int loff = l31 * 8;
    char* wb = &shalpha[w * 1536];
    const char* ab2 = wb + 256 + hq * 260;
    const char* embByte = (const char*)embBf;

    for (int it = 0; it < 4; ++it) {
        int nd = it * 8 + w;
        int n = b * 32 + nd;
        if (n >= N) break;
        int st0 = scn32[nd];
        int deg = scn32[nd + 1] - st0;
        float4 hrv = *(const float4*)&h_r[(size_t)n * 4];

        if (deg <= 64) {
            bool act = lane < deg;
            float p0 = 0.f, p1 = 0.f, p2 = 0.f, p3 = 0.f;
            int roval = 0;
            if (act) {
                int pk = sedge[st0 + lane];
                roval = (pk & 0xffff) << 8;     // emb byte offset
                float4 hl = *(const float4*)&h_l[(size_t)(pk & 0xffff) * 4];
                float4 he = *(const float4*)&h_e_t[(size_t)(pk >> 16) * 4];
                float sc0 = hl.x + he.x + hrv.x; sc0 = sc0 > 0.f ? sc0 : NEG_SLOPE * sc0;
                float sc1 = hl.y + he.y + hrv.y; sc1 = sc1 > 0.f ? sc1 : NEG_SLOPE * sc1;
                float sc2 = hl.z + he.z + hrv.z; sc2 = sc2 > 0.f ? sc2 : NEG_SLOPE * sc2;
                float sc3 = hl.w + he.w + hrv.w; sc3 = sc3 > 0.f ? sc3 : NEG_SLOPE * sc3;
                p0 = __expf(sc0); p1 = __expf(sc1);
                p2 = __expf(sc2); p3 = __expf(sc3);
            }
            // park ALL lanes (zero padding -> no clamp in gather loop)
            *(int*)(wb + lane * 4) = roval;
            *(float*)(wb + 256 + 0 * 260 + lane * 4) = p0;
            *(float*)(wb + 256 + 1 * 260 + lane * 4) = p1;
            *(float*)(wb + 256 + 2 * 260 + lane * 4) = p2;
            *(float*)(wb + 256 + 3 * 260 + lane * 4) = p3;

            float d0 = p0, d1 = p1, d2 = p2, d3 = p3;
#pragma unroll
            for (int off = 32; off >= 1; off >>= 1) {
                d0 += __shfl_xor(d0, off); d1 += __shfl_xor(d1, off);
                d2 += __shfl_xor(d2, off); d3 += __shfl_xor(d3, off);
            }
            float den = hq == 0 ? d0 : hq == 1 ? d1 : hq == 2 ? d2 : d3;
            float inv = (deg > 0) ? __builtin_amdgcn_rcpf(den) : 0.f;

            f32x4 acc4 = (f32x4){0.f, 0.f, 0.f, 0.f};
            for (int q = 0; q < deg; q += 8) {  // 4 pairs = 8 edges; tail = zeros
                int ro[4]; float aq[4];
#pragma unroll
                for (int u = 0; u < 4; ++u) {
                    int qe = q + 2 * u + sel;
                    ro[u] = *(const int*)(wb + qe * 4);
                    aq[u] = *(const float*)(ab2 + qe * 4);
                }
                uint2 ev[4];
#pragma unroll
                for (int u = 0; u < 4; ++u)
                    ev[u] = *(const uint2*)(embByte + (size_t)(unsigned)(ro[u] + loff));
#pragma unroll
                for (int u = 0; u < 4; ++u) {
                    f32x4 ef;
                    ef.x = __builtin_bit_cast(float, ev[u].x << 16);
                    ef.y = __builtin_bit_cast(float, ev[u].x & 0xffff0000u);
                    ef.z = __builtin_bit_cast(float, ev[u].y << 16);
                    ef.w = __builtin_bit_cast(float, ev[u].y & 0xffff0000u);
                    acc4 = __builtin_elementwise_fma(
                        ef, (f32x4){aq[u], aq[u], aq[u], aq[u]}, acc4);
                }
            }
            acc4.x += __shfl_xor(acc4.x, 32);
            acc4.y += __shfl_xor(acc4.y, 32);
            acc4.z += __shfl_xor(acc4.z, 32);
            acc4.w += __shfl_xor(acc4.w, 32);
            float vlo = sel ? acc4.z : acc4.x;
            float vhi = sel ? acc4.w : acc4.y;

            int j0 = l31 * 4 + sel * 2;         // flat j = h*32+d
            int h0 = j0 >> 5, dd = j0 & 31;
            size_t ob = (size_t)n * 128;
            float o0 = vlo * inv + bf2f(resBf[ob + dd * 4 + h0]);
            float o1 = vhi * inv + bf2f(resBf[ob + (dd + 1) * 4 + h0]);
            out[ob + dd * 4 + h0] = o0 > 0.f ? o0 : expm1f(o0);
            out[ob + (dd + 1) * 4 + h0] = o1 > 0.f ? o1 : expm1f(o1);
        } else {
            // ---- chunked fallback (deg>64, rare): 2-elem/lane layout ----
            f32x2 acc2 = (f32x2){0.f, 0.f};
            float d0 = 0.f, d1 = 0.f, d2 = 0.f, d3 = 0.f;
            for (int base2 = 0; base2 < deg; base2 += 64) {
                int el = base2 + lane;
                if (el < deg) {
                    int pk = sedge[st0 + el];
                    float4 hl = *(const float4*)&h_l[(size_t)(pk & 0xffff) * 4];
                    float4 he = *(const float4*)&h_e_t[(size_t)(pk >> 16) * 4];
                    float sc0 = hl.x + he.x + hrv.x; sc0 = sc0 > 0.f ? sc0 : NEG_SLOPE * sc0;
                    float sc1 = hl.y + he.y + hrv.y; sc1 = sc1 > 0.f ? sc1 : NEG_SLOPE * sc1;
                    float sc2 = hl.z + he.z + hrv.z; sc2 = sc2 > 0.f ? sc2 : NEG_SLOPE * sc2;
                    float sc3 = hl.w + he.w + hrv.w; sc3 = sc3 > 0.f ? sc3 : NEG_SLOPE * sc3;
                    d0 += __expf(sc0); d1 += __expf(sc1);
                    d2 += __expf(sc2); d3 += __expf(sc3);
                }
            }
#pragma unroll
            for (int off = 32; off >= 1; off >>= 1) {
                d0 += __shfl_xor(d0, off); d1 += __shfl_xor(d1, off);
                d2 += __shfl_xor(d2, off); d3 += __shfl_xor(d3, off);
            }
            float den = myh == 0 ? d0 : myh == 1 ? d1 : myh == 2 ? d2 : d3;
            float inv = __builtin_amdgcn_rcpf(den);
            for (int base2 = 0; base2 < deg; base2 += 64) {
                int el = base2 + lane;
                float p0 = 0.f, p1 = 0.f, p2 = 0.f, p3 = 0.f;
                int r = 0;
                if (el < deg) {
                    int pk = sedge[st0 + el];
                    r = pk & 0xffff;
                    float4 hl = *(const float4*)&h_l[(size_t)r * 4];
                    float4 he = *(const float4*)&h_e_t[(size_t)(pk >> 16) * 4];
                    float sc0 = hl.x + he.x + hrv.x; sc0 = sc0 > 0.f ? sc0 : NEG_SLOPE * sc0;
                    float sc1 = hl.y + he.y + hrv.y; sc1 = sc1 > 0.f ? sc1 : NEG_SLOPE * sc1;
                    float sc2 = hl.z + he.z + hrv.z; sc2 = sc2 > 0.f ? sc2 : NEG_SLOPE * sc2;
                    float sc3 = hl.w + he.w + hrv.w; sc3 = sc3 > 0.f ? sc3 : NEG_SLOPE * sc3;
                    p0 = __expf(sc0); p1 = __expf(sc1);
                    p2 = __expf(sc2); p3 = __expf(sc3);
                }
                int cmax = (deg - base2 < 64) ? (deg - base2) : 64;
                for (int qq = 0; qq < cmax; ++qq) {
                    int rq = __shfl(r, qq);
                    float a0 = __shfl(p0, qq), a1 = __shfl(p1, qq);
                    float a2 = __shfl(p2, qq), a3 = __shfl(p3, qq);
                    float aqv = myh == 0 ? a0 : myh == 1 ? a1 : myh == 2 ? a2 : a3;
                    unsigned int ev = *(const unsigned int*)&embBf[(size_t)rq * 128 + lane * 2];
                    f32x2 ef;
                    ef.x = __builtin_bit_cast(float, ev << 16);
                    ef.y = __builtin_bit_cast(float, ev & 0xffff0000u);
                    acc2 = __builtin_elementwise_fma(ef, (f32x2){aqv, aqv}, acc2);
                }
            }
            int j0 = lane * 2;
            int h0 = j0 >> 5, dd0 = j0 & 31;
            size_t ob = (size_t)n * 128;
            float o0 = acc2.x * inv + bf2f(resBf[ob + dd0 * 4 + h0]);
            float o1 = acc2.y * inv + bf2f(resBf[ob + (dd0 + 1) * 4 + h0]);
            out[ob + dd0 * 4 + h0] = o0 > 0.f ? o0 : expm1f(o0);
            out[ob + (dd0 + 1) * 4 + h0] = o1 > 0.f ? o1 : expm1f(o1);
        }
    }
}

// ---------------------------------------------------------------------------
extern "C" void kernel_launch(void* const* d_in, const int* in_sizes, int n_in,
                              void* d_out, int out_size, void* d_ws, size_t ws_size,
                              hipStream_t stream)
{
    const float* h        = (const float*)d_in[0];
    const float* W        = (const float*)d_in[1];
    const float* edge_emb = (const float*)d_in[2];
    const float* W_r      = (const float*)d_in[3];
    const float* a_l      = (const float*)d_in[4];
    const float* a_r      = (const float*)d_in[5];
    const float* a_e      = (const float*)d_in[6];
    const float* res_w    = (const float*)d_in[7];
    const float* res_b    = (const float*)d_in[8];
    const int*   row      = (const int*)d_in[9];
    const int*   col      = (const int*)d_in[10];
    const int*   etype    = (const int*)d_in[11];
    float* out = (float*)d_out;

    int N = in_sizes[0] / 128;
    int E = in_sizes[9];
    int T = in_sizes[2] / EDIM;
    int NB = (N + 31) >> BSH;                   // 32-node buckets

    int nFill = (E + 8191) / 8192;              // <= 128 for this problem
    int nGemm = (N + 63) / 64;

    char* ws = (char*)d_ws;
    size_t off = 0;
    auto alloc = [&](size_t bytes) -> char* {
        char* p = ws + off;
        off = (off + bytes + 255) & ~(size_t)255;
        return p;
    };
    unsigned short* embBf = (unsigned short*)alloc((size_t)N * 128 * 2);
    unsigned short* resBf = (unsigned short*)alloc((size_t)N * 128 * 2);
    unsigned short* Wt    = (unsigned short*)alloc((size_t)128 * 128 * 2);
    unsigned short* Rwt   = (unsigned short*)alloc((size_t)128 * 128 * 2);
    float* h_l   = (float*)alloc((size_t)N * 4 * 4);
    float* h_r   = (float*)alloc((size_t)N * 4 * 4);
    float* h_e_t = (float*)alloc((size_t)T * NH * 4);
    unsigned* meta = (unsigned*)alloc((size_t)nFill * NB * 4);
    unsigned* ebuf = (unsigned*)alloc((size_t)nFill * 8192 * 4);

    hipLaunchKernelGGL(k_prep, dim3(64 + T), dim3(256), 0, stream,
                       W, res_w, Wt, Rwt, edge_emb, W_r, a_e, h_e_t);
    hipLaunchKernelGGL(k_gemm_fill, dim3(nFill + nGemm), dim3(256), 0, stream,
                       h, Wt, Rwt, res_b, a_l, a_r, embBf, resBf, h_l, h_r, N,
                       row, col, etype, meta, ebuf, E, NB, nFill);
    hipLaunchKernelGGL(k_sort_aggregate, dim3(NB), dim3(512), 0, stream,
                       ebuf, meta, nFill, NB, h_l, h_e_t, h_r, embBf, resBf, out, N);
}

// Round 18
// 86.562 us; speedup vs baseline: 1.0584x; 1.0584x over previous
//
#include <hip/hip_runtime.h>
#include <math.h>

#define NH 4
#define EDIM 32
#define NEG_SLOPE 0.2f
#define BSH 5                  // bucket = col>>5 (32 nodes per bucket)
#define BCAP 1024              // fixed capacity per bucket segment (mean ~512)

typedef __attribute__((ext_vector_type(8))) short short8;
typedef __attribute__((ext_vector_type(4))) float f32x4;
typedef __attribute__((ext_vector_type(2))) float f32x2;

__device__ __forceinline__ unsigned short f2bf(float f) {
    unsigned int x = __builtin_bit_cast(unsigned int, f);
    unsigned int r = (x + 0x7fffu + ((x >> 16) & 1u)) >> 16;
    return (unsigned short)r;
}
__device__ __forceinline__ float bf2f(unsigned short u) {
    unsigned int x = ((unsigned int)u) << 16;
    return __builtin_bit_cast(float, x);
}

// ---------------------------------------------------------------------------
// Prep: blocks [0,64): weight transpose+bf16 + zero bucket cursors.
//       blocks [64,64+T): h_e_t for one edge type each.
__global__ __launch_bounds__(256) void k_prep(
    const float* __restrict__ W, const float* __restrict__ Rw,
    unsigned short* __restrict__ Wt, unsigned short* __restrict__ Rwt,
    int* __restrict__ bucket_cursor,
    const float* __restrict__ edge_emb, const float* __restrict__ W_r,
    const float* __restrict__ a_e, float* __restrict__ h_e_t)
{
    int tid = threadIdx.x;
    if (blockIdx.x < 64) {
        int idx = blockIdx.x * 256 + tid;       // 0..16383
        int n = idx >> 7, k = idx & 127;
        Wt[n * 128 + k]  = f2bf(W[k * 128 + n]);
        Rwt[n * 128 + k] = f2bf(Rw[k * 128 + n]);
        if (idx < 2048) bucket_cursor[idx] = 0;
        return;
    }
    int t = blockIdx.x - 64;
    if (tid < 128) {
        int rem = tid;                          // h*32+k
        float v = 0.f;
#pragma unroll
        for (int e = 0; e < EDIM; ++e)
            v += edge_emb[t * EDIM + e] * W_r[(size_t)(t * EDIM + e) * 128 + rem];
        v *= a_e[rem];
#pragma unroll
        for (int off = 16; off >= 1; off >>= 1)
            v += __shfl_xor(v, off);
        if ((rem & 31) == 0) h_e_t[t * NH + (rem >> 5)] = v;
    }
}

// ---------------------------------------------------------------------------
// Merged: blocks [0,nFill) = bucket scatter (8192 edges each);
//         blocks [nFill,..) = MFMA GEMM with 32KB LDS (A + half-B staging).
__global__ __launch_bounds__(256) void k_gemm_fill(
    const float* __restrict__ A, const unsigned short* __restrict__ Wt,
    const unsigned short* __restrict__ Rwt, const float* __restrict__ Rb,
    const float* __restrict__ a_l, const float* __restrict__ a_r,
    unsigned short* __restrict__ EmbBf, unsigned short* __restrict__ ResBf,
    float* __restrict__ h_l, float* __restrict__ h_r, int M,
    const int* __restrict__ row, const int* __restrict__ col,
    const int* __restrict__ etype, int* __restrict__ bucket_cursor,
    unsigned* __restrict__ ebuf, int E, int NB, int nFill)
{
    __shared__ char lds[32768];                 // [0,16K) A ; [16K,32K) B-half
    int tid = threadIdx.x;

    if ((int)blockIdx.x < nFill) {
        // ---- single-pass bucket scatter into fixed-capacity segments ----
        int* bins = (int*)lds;
        int* base = bins + 2048;
        for (int i = tid; i < NB; i += 256) bins[i] = 0;
        __syncthreads();
        int lo = blockIdx.x * 8192;
        int ccol[32];
#pragma unroll
        for (int u = 0; u < 32; ++u) {
            int i = lo + tid + u * 256;
            int c = (i < E) ? col[i] : -1;
            ccol[u] = c;
            if (c >= 0) atomicAdd(&bins[c >> BSH], 1);
        }
        __syncthreads();
        for (int i = tid; i < NB; i += 256) {
            int c = bins[i];
            base[i] = c ? atomicAdd(&bucket_cursor[i], c) : 0;
            bins[i] = 0;                        // reuse as local cursor
        }
        __syncthreads();
#pragma unroll
        for (int u = 0; u < 32; ++u) {
            int i = lo + tid + u * 256;
            int c = ccol[u];
            if (c >= 0) {
                int bk = c >> BSH;
                int p = bk * BCAP + base[bk] + atomicAdd(&bins[bk], 1);
                ebuf[p] = (unsigned)row[i] | ((unsigned)etype[i] << 16)
                        | ((unsigned)(c & 31) << 24);
            }
        }
        return;
    }

    // ---- MFMA GEMM ----
    int m0 = ((int)blockIdx.x - nFill) * 64;
#pragma unroll
    for (int i = 0; i < 4; ++i) {
        int c = tid + 256 * i;                  // 0..1023
        int r = c >> 4, kc = c & 15;
        int grow = m0 + r;
        float4 v0 = make_float4(0.f, 0.f, 0.f, 0.f), v1 = v0;
        if (grow < M) {
            v0 = *(const float4*)&A[(size_t)grow * 128 + kc * 8];
            v1 = *(const float4*)&A[(size_t)grow * 128 + kc * 8 + 4];
        }
        union { unsigned short u[8]; uint4 v; } p;
        p.u[0] = f2bf(v0.x); p.u[1] = f2bf(v0.y); p.u[2] = f2bf(v0.z); p.u[3] = f2bf(v0.w);
        p.u[4] = f2bf(v1.x); p.u[5] = f2bf(v1.y); p.u[6] = f2bf(v1.z); p.u[7] = f2bf(v1.w);
        int b = (r * 256 + kc * 16) ^ ((r & 7) << 4);
        *(uint4*)&lds[b] = p.v;
    }

    int w = tid >> 6, lane = tid & 63;
    int g = lane >> 4, l15 = lane & 15;
    int lrow = w * 16 + l15;

    auto stageB = [&](const unsigned short* src) {
#pragma unroll
        for (int i = 0; i < 4; ++i) {
            int c = tid + 256 * i;              // 0..1023
            int n2 = c >> 4, kc = c & 15;
            uint4 v = *(const uint4*)&src[n2 * 128 + kc * 8];
            int b = 16384 + ((n2 * 256 + kc * 16) ^ ((n2 & 7) << 4));
            *(uint4*)&lds[b] = v;
        }
    };
    auto computeHalf = [&](f32x4* accp, const short8* a) {
#pragma unroll
        for (int f = 0; f < 4; ++f) {
            int n2 = f * 16 + l15;
            int nsw = (n2 & 7) << 4;
#pragma unroll
            for (int s = 0; s < 4; ++s) {
                short8 b = *(const short8*)&lds[16384 + ((n2 * 256 + s * 64 + g * 16) ^ nsw)];
                accp[f] = __builtin_amdgcn_mfma_f32_16x16x32_bf16(a[s], b, accp[f], 0, 0, 0);
            }
        }
    };

    stageB(Wt);
    __syncthreads();

    short8 a[4];
#pragma unroll
    for (int s = 0; s < 4; ++s)
        a[s] = *(const short8*)&lds[(lrow * 256 + s * 64 + g * 16) ^ ((lrow & 7) << 4)];

    f32x4 acc[8];
#pragma unroll
    for (int f = 0; f < 8; ++f) acc[f] = (f32x4){0.f, 0.f, 0.f, 0.f};

    computeHalf(&acc[0], a);                    // cols 0..63
    __syncthreads();
    stageB(Wt + 64 * 128);
    __syncthreads();
    computeHalf(&acc[4], a);                    // cols 64..127

#pragma unroll
    for (int f = 0; f < 8; ++f) {
        int col2 = f * 16 + l15;
#pragma unroll
        for (int reg = 0; reg < 4; ++reg) {
            int grow = m0 + w * 16 + g * 4 + reg;
            if (grow < M) EmbBf[(size_t)grow * 128 + col2] = f2bf(acc[f][reg]);
        }
    }
    {
        float alv[8], arv[8];
#pragma unroll
        for (int f = 0; f < 8; ++f) {
            alv[f] = a_l[f * 16 + l15];
            arv[f] = a_r[f * 16 + l15];
        }
#pragma unroll
        for (int reg = 0; reg < 4; ++reg) {
            float4 hl4, hr4;
#pragma unroll
            for (int hh = 0; hh < 4; ++hh) {
                float pl = alv[2 * hh] * acc[2 * hh][reg] + alv[2 * hh + 1] * acc[2 * hh + 1][reg];
                float pr = arv[2 * hh] * acc[2 * hh][reg] + arv[2 * hh + 1] * acc[2 * hh + 1][reg];
#pragma unroll
                for (int off = 8; off >= 1; off >>= 1) {
                    pl += __shfl_xor(pl, off);
                    pr += __shfl_xor(pr, off);
                }
                (&hl4.x)[hh] = pl;
                (&hr4.x)[hh] = pr;
            }
            int grow = m0 + w * 16 + g * 4 + reg;
            if (l15 == 0 && grow < M) {
                *(float4*)&h_l[(size_t)grow * 4] = hl4;
                *(float4*)&h_r[(size_t)grow * 4] = hr4;
            }
        }
    }

    // ---- res pass ----
    __syncthreads();
    stageB(Rwt);
    __syncthreads();
#pragma unroll
    for (int f = 0; f < 8; ++f) acc[f] = (f32x4){0.f, 0.f, 0.f, 0.f};
    computeHalf(&acc[0], a);
    __syncthreads();
    stageB(Rwt + 64 * 128);
    __syncthreads();
    computeHalf(&acc[4], a);

#pragma unroll
    for (int f = 0; f < 8; ++f) {
        int col2 = f * 16 + l15;
        float bias = Rb[col2];
#pragma unroll
        for (int reg = 0; reg < 4; ++reg) {
            int grow = m0 + w * 16 + g * 4 + reg;
            if (grow < M) ResBf[(size_t)grow * 128 + col2] = f2bf(acc[f][reg] + bias);
        }
    }
}

// ---------------------------------------------------------------------------
// Fused within-bucket sort + aggregate.  512 threads (8 waves) per 32-node
// bucket.  NEW: half-wave node pairing — lanes 0-31 own node A, 32-63 node B
// (deg<=32 covers ~99.98%); scoring/park/tree run at 2x utilization, gather
// is half-wave-local (no cross-half combines).  Full-wave fallback otherwise.
__global__ __launch_bounds__(512) void k_sort_aggregate(
    const unsigned* __restrict__ ebuf, const int* __restrict__ bucket_cursor,
    const float* __restrict__ h_l, const float* __restrict__ h_e_t,
    const float* __restrict__ h_r, const unsigned short* __restrict__ embBf,
    const unsigned short* __restrict__ resBf, float* __restrict__ out, int N)
{
    __shared__ int sedge[BCAP];
    __shared__ int cnt[32];
    __shared__ int scn[33];
    __shared__ char shalpha[8 * 1536];

    int b = blockIdx.x;
    int tid = threadIdx.x;
    int seg = b * BCAP;
    int m = bucket_cursor[b];                   // relative count

    if (tid < 32) cnt[tid] = 0;
    __syncthreads();
    for (int i = tid; i < m; i += 512)
        atomicAdd(&cnt[(ebuf[seg + i] >> 24) & 31], 1);
    __syncthreads();
    if (tid < 32) {
        int v = cnt[tid];
        int s = v;
#pragma unroll
        for (int off = 1; off < 32; off <<= 1) {
            int u2 = __shfl_up(s, off);
            if (tid >= off) s += u2;
        }
        scn[tid + 1] = s;
        if (tid == 0) scn[0] = 0;
        cnt[tid] = s - v;                       // exclusive; reuse as cursor
    }
    __syncthreads();
    for (int i = tid; i < m; i += 512) {
        unsigned e = ebuf[seg + i];
        int p = atomicAdd(&cnt[(e >> 24) & 31], 1);
        sedge[p] = (int)(e & 0x00FFFFFF);
    }
    __syncthreads();

    int w = tid >> 6, lane = tid & 63;
    int myh = lane >> 4;                        // fallback-path head
    int l31 = lane & 31;
    int sel = lane >> 5;                        // half index / pair parity
    int hq = l31 >> 3;                          // gather head (elements l31*4..+3)
    int loff = l31 * 8;
    char* wb = &shalpha[w * 1536];
    const char* ab2 = wb + 256 + hq * 260;
    const char* embByte = (const char*)embBf;

    for (int it = 0; it < 2; ++it) {
        int ndA = it * 16 + w * 2;              // wave owns nodes ndA, ndA+1
        int degA = scn[ndA + 1] - scn[ndA];
        int degB = scn[ndA + 2] - scn[ndA + 1];

        if (degA <= 32 && degB <= 32) {
            // ---- paired half-wave path ----
            int nd = ndA + sel;
            int n = b * 32 + nd;
            bool okn = (n < N);
            int st0 = scn[nd];
            int deg = scn[nd + 1] - st0;
            int nsafe = okn ? n : 0;
            float4 hrv = *(const float4*)&h_r[(size_t)nsafe * 4];
            bool act = okn && (l31 < deg);
            float p0 = 0.f, p1 = 0.f, p2 = 0.f, p3 = 0.f;
            int roval = 0;
            if (act) {
                int pk = sedge[st0 + l31];
                roval = (pk & 0xffff) << 8;     // emb byte offset
                float4 hl = *(const float4*)&h_l[(size_t)(pk & 0xffff) * 4];
                float4 he = *(const float4*)&h_e_t[(size_t)(pk >> 16) * 4];
                float sc0 = hl.x + he.x + hrv.x; sc0 = sc0 > 0.f ? sc0 : NEG_SLOPE * sc0;
                float sc1 = hl.y + he.y + hrv.y; sc1 = sc1 > 0.f ? sc1 : NEG_SLOPE * sc1;
                float sc2 = hl.z + he.z + hrv.z; sc2 = sc2 > 0.f ? sc2 : NEG_SLOPE * sc2;
                float sc3 = hl.w + he.w + hrv.w; sc3 = sc3 > 0.f ? sc3 : NEG_SLOPE * sc3;
                p0 = __expf(sc0); p1 = __expf(sc1);
                p2 = __expf(sc2); p3 = __expf(sc3);
            }
            // park all lanes (slot = lane; half A -> 0..31, half B -> 32..63)
            *(int*)(wb + lane * 4) = roval;
            *(float*)(wb + 256 + 0 * 260 + lane * 4) = p0;
            *(float*)(wb + 256 + 1 * 260 + lane * 4) = p1;
            *(float*)(wb + 256 + 2 * 260 + lane * 4) = p2;
            *(float*)(wb + 256 + 3 * 260 + lane * 4) = p3;

            // half-local denominator tree
            float d0 = p0, d1 = p1, d2 = p2, d3 = p3;
#pragma unroll
            for (int off = 16; off >= 1; off >>= 1) {
                d0 += __shfl_xor(d0, off); d1 += __shfl_xor(d1, off);
                d2 += __shfl_xor(d2, off); d3 += __shfl_xor(d3, off);
            }
            float den = hq == 0 ? d0 : hq == 1 ? d1 : hq == 2 ? d2 : d3;
            float inv = (deg > 0) ? __builtin_amdgcn_rcpf(den) : 0.f;

            int degmax = degA > degB ? degA : degB;
            int sb = lane & 32;                 // my half's slot base
            f32x4 acc4 = (f32x4){0.f, 0.f, 0.f, 0.f};
            for (int q = 0; q < degmax; q += 8) {
                int ro[8]; float aq[8];
#pragma unroll
                for (int u = 0; u < 8; ++u) {
                    int slot = sb + q + u;
                    ro[u] = *(const int*)(wb + slot * 4);
                    aq[u] = *(const float*)(ab2 + slot * 4);
                }
                uint2 ev[8];
#pragma unroll
                for (int u = 0; u < 8; ++u)
                    ev[u] = *(const uint2*)(embByte + (size_t)(unsigned)(ro[u] + loff));
#pragma unroll
                for (int u = 0; u < 8; ++u) {
                    f32x4 ef;
                    ef.x = __builtin_bit_cast(float, ev[u].x << 16);
                    ef.y = __builtin_bit_cast(float, ev[u].x & 0xffff0000u);
                    ef.z = __builtin_bit_cast(float, ev[u].y << 16);
                    ef.w = __builtin_bit_cast(float, ev[u].y & 0xffff0000u);
                    acc4 = __builtin_elementwise_fma(
                        ef, (f32x4){aq[u], aq[u], aq[u], aq[u]}, acc4);
                }
            }
            if (okn) {
                int h0 = hq;
                int ddb = (l31 & 7) * 4;
                size_t ob = (size_t)n * 128;
#pragma unroll
                for (int u = 0; u < 4; ++u) {
                    float o = acc4[u] * inv + bf2f(resBf[ob + (ddb + u) * 4 + h0]);
                    out[ob + (ddb + u) * 4 + h0] = o > 0.f ? o : expm1f(o);
                }
            }
            continue;
        }

        // ---- fallback: process each node with the full wave (rare) ----
        for (int pick = 0; pick < 2; ++pick) {
            int nd = ndA + pick;
            int n = b * 32 + nd;
            if (n >= N) continue;
            int st0 = scn[nd];
            int deg = scn[nd + 1] - st0;
            float4 hrv = *(const float4*)&h_r[(size_t)n * 4];

            if (deg <= 64) {
                bool act = lane < deg;
                float p0 = 0.f, p1 = 0.f, p2 = 0.f, p3 = 0.f;
                int roval = 0;
                if (act) {
                    int pk = sedge[st0 + lane];
                    roval = (pk & 0xffff) << 8;
                    float4 hl = *(const float4*)&h_l[(size_t)(pk & 0xffff) * 4];
                    float4 he = *(const float4*)&h_e_t[(size_t)(pk >> 16) * 4];
                    float sc0 = hl.x + he.x + hrv.x; sc0 = sc0 > 0.f ? sc0 : NEG_SLOPE * sc0;
                    float sc1 = hl.y + he.y + hrv.y; sc1 = sc1 > 0.f ? sc1 : NEG_SLOPE * sc1;
                    float sc2 = hl.z + he.z + hrv.z; sc2 = sc2 > 0.f ? sc2 : NEG_SLOPE * sc2;
                    float sc3 = hl.w + he.w + hrv.w; sc3 = sc3 > 0.f ? sc3 : NEG_SLOPE * sc3;
                    p0 = __expf(sc0); p1 = __expf(sc1);
                    p2 = __expf(sc2); p3 = __expf(sc3);
                }
                *(int*)(wb + lane * 4) = roval;
                *(float*)(wb + 256 + 0 * 260 + lane * 4) = p0;
                *(float*)(wb + 256 + 1 * 260 + lane * 4) = p1;
                *(float*)(wb + 256 + 2 * 260 + lane * 4) = p2;
                *(float*)(wb + 256 + 3 * 260 + lane * 4) = p3;

                float d0 = p0, d1 = p1, d2 = p2, d3 = p3;
#pragma unroll
                for (int off = 32; off >= 1; off >>= 1) {
                    d0 += __shfl_xor(d0, off); d1 += __shfl_xor(d1, off);
                    d2 += __shfl_xor(d2, off); d3 += __shfl_xor(d3, off);
                }
                float den = hq == 0 ? d0 : hq == 1 ? d1 : hq == 2 ? d2 : d3;
                float inv = (deg > 0) ? __builtin_amdgcn_rcpf(den) : 0.f;

                f32x4 acc4 = (f32x4){0.f, 0.f, 0.f, 0.f};
                for (int q = 0; q < deg; q += 8) {
                    int ro[4]; float aq[4];
#pragma unroll
                    for (int u = 0; u < 4; ++u) {
                        int qe = q + 2 * u + sel;
                        ro[u] = *(const int*)(wb + qe * 4);
                        aq[u] = *(const float*)(ab2 + qe * 4);
                    }
                    uint2 ev[4];
#pragma unroll
                    for (int u = 0; u < 4; ++u)
                        ev[u] = *(const uint2*)(embByte + (size_t)(unsigned)(ro[u] + loff));
#pragma unroll
                    for (int u = 0; u < 4; ++u) {
                        f32x4 ef;
                        ef.x = __builtin_bit_cast(float, ev[u].x << 16);
                        ef.y = __builtin_bit_cast(float, ev[u].x & 0xffff0000u);
                        ef.z = __builtin_bit_cast(float, ev[u].y << 16);
                        ef.w = __builtin_bit_cast(float, ev[u].y & 0xffff0000u);
                        acc4 = __builtin_elementwise_fma(
                            ef, (f32x4){aq[u], aq[u], aq[u], aq[u]}, acc4);
                    }
                }
                acc4.x += __shfl_xor(acc4.x, 32);
                acc4.y += __shfl_xor(acc4.y, 32);
                acc4.z += __shfl_xor(acc4.z, 32);
                acc4.w += __shfl_xor(acc4.w, 32);
                float vlo = sel ? acc4.z : acc4.x;
                float vhi = sel ? acc4.w : acc4.y;

                int j0 = l31 * 4 + sel * 2;
                int h0 = j0 >> 5, dd = j0 & 31;
                size_t ob = (size_t)n * 128;
                float o0 = vlo * inv + bf2f(resBf[ob + dd * 4 + h0]);
                float o1 = vhi * inv + bf2f(resBf[ob + (dd + 1) * 4 + h0]);
                out[ob + dd * 4 + h0] = o0 > 0.f ? o0 : expm1f(o0);
                out[ob + (dd + 1) * 4 + h0] = o1 > 0.f ? o1 : expm1f(o1);
            } else {
                // chunked path (deg>64, very rare): 2-elem/lane layout
                f32x2 acc2 = (f32x2){0.f, 0.f};
                float d0 = 0.f, d1 = 0.f, d2 = 0.f, d3 = 0.f;
                for (int base2 = 0; base2 < deg; base2 += 64) {
                    int el = base2 + lane;
                    if (el < deg) {
                        int pk = sedge[st0 + el];
                        float4 hl = *(const float4*)&h_l[(size_t)(pk & 0xffff) * 4];
                        float4 he = *(const float4*)&h_e_t[(size_t)(pk >> 16) * 4];
                        float sc0 = hl.x + he.x + hrv.x; sc0 = sc0 > 0.f ? sc0 : NEG_SLOPE * sc0;
                        float sc1 = hl.y + he.y + hrv.y; sc1 = sc1 > 0.f ? sc1 : NEG_SLOPE * sc1;
                        float sc2 = hl.z + he.z + hrv.z; sc2 = sc2 > 0.f ? sc2 : NEG_SLOPE * sc2;
                        float sc3 = hl.w + he.w + hrv.w; sc3 = sc3 > 0.f ? sc3 : NEG_SLOPE * sc3;
                        d0 += __expf(sc0); d1 += __expf(sc1);
                        d2 += __expf(sc2); d3 += __expf(sc3);
                    }
                }
#pragma unroll
                for (int off = 32; off >= 1; off >>= 1) {
                    d0 += __shfl_xor(d0, off); d1 += __shfl_xor(d1, off);
                    d2 += __shfl_xor(d2, off); d3 += __shfl_xor(d3, off);
                }
                float den = myh == 0 ? d0 : myh == 1 ? d1 : myh == 2 ? d2 : d3;
                float inv = __builtin_amdgcn_rcpf(den);
                for (int base2 = 0; base2 < deg; base2 += 64) {
                    int el = base2 + lane;
                    float p0 = 0.f, p1 = 0.f, p2 = 0.f, p3 = 0.f;
                    int r = 0;
                    if (el < deg) {
                        int pk = sedge[st0 + el];
                        r = pk & 0xffff;
                        float4 hl = *(const float4*)&h_l[(size_t)r * 4];
                        float4 he = *(const float4*)&h_e_t[(size_t)(pk >> 16) * 4];
                        float sc0 = hl.x + he.x + hrv.x; sc0 = sc0 > 0.f ? sc0 : NEG_SLOPE * sc0;
                        float sc1 = hl.y + he.y + hrv.y; sc1 = sc1 > 0.f ? sc1 : NEG_SLOPE * sc1;
                        float sc2 = hl.z + he.z + hrv.z; sc2 = sc2 > 0.f ? sc2 : NEG_SLOPE * sc2;
                        float sc3 = hl.w + he.w + hrv.w; sc3 = sc3 > 0.f ? sc3 : NEG_SLOPE * sc3;
                        p0 = __expf(sc0); p1 = __expf(sc1);
                        p2 = __expf(sc2); p3 = __expf(sc3);
                    }
                    int cmax = (deg - base2 < 64) ? (deg - base2) : 64;
                    for (int qq = 0; qq < cmax; ++qq) {
                        int rq = __shfl(r, qq);
                        float a0 = __shfl(p0, qq), a1 = __shfl(p1, qq);
                        float a2 = __shfl(p2, qq), a3 = __shfl(p3, qq);
                        float aqv = myh == 0 ? a0 : myh == 1 ? a1 : myh == 2 ? a2 : a3;
                        unsigned int ev = *(const unsigned int*)&embBf[(size_t)rq * 128 + lane * 2];
                        f32x2 ef;
                        ef.x = __builtin_bit_cast(float, ev << 16);
                        ef.y = __builtin_bit_cast(float, ev & 0xffff0000u);
                        acc2 = __builtin_elementwise_fma(ef, (f32x2){aqv, aqv}, acc2);
                    }
                }
                int j0 = lane * 2;
                int h0 = j0 >> 5, dd0 = j0 & 31;
                size_t ob = (size_t)n * 128;
                float o0 = acc2.x * inv + bf2f(resBf[ob + dd0 * 4 + h0]);
                float o1 = acc2.y * inv + bf2f(resBf[ob + (dd0 + 1) * 4 + h0]);
                out[ob + dd0 * 4 + h0] = o0 > 0.f ? o0 : expm1f(o0);
                out[ob + (dd0 + 1) * 4 + h0] = o1 > 0.f ? o1 : expm1f(o1);
            }
        }
    }
}

// ---------------------------------------------------------------------------
extern "C" void kernel_launch(void* const* d_in, const int* in_sizes, int n_in,
                              void* d_out, int out_size, void* d_ws, size_t ws_size,
                              hipStream_t stream)
{
    const float* h        = (const float*)d_in[0];
    const float* W        = (const float*)d_in[1];
    const float* edge_emb = (const float*)d_in[2];
    const float* W_r      = (const float*)d_in[3];
    const float* a_l      = (const float*)d_in[4];
    const float* a_r      = (const float*)d_in[5];
    const float* a_e      = (const float*)d_in[6];
    const float* res_w    = (const float*)d_in[7];
    const float* res_b    = (const float*)d_in[8];
    const int*   row      = (const int*)d_in[9];
    const int*   col      = (const int*)d_in[10];
    const int*   etype    = (const int*)d_in[11];
    float* out = (float*)d_out;

    int N = in_sizes[0] / 128;
    int E = in_sizes[9];
    int T = in_sizes[2] / EDIM;
    int NB = (N + 31) >> BSH;                   // 32-node buckets

    char* ws = (char*)d_ws;
    size_t off = 0;
    auto alloc = [&](size_t bytes) -> char* {
        char* p = ws + off;
        off = (off + bytes + 255) & ~(size_t)255;
        return p;
    };
    unsigned short* embBf = (unsigned short*)alloc((size_t)N * 128 * 2);
    unsigned short* resBf = (unsigned short*)alloc((size_t)N * 128 * 2);
    unsigned short* Wt    = (unsigned short*)alloc((size_t)128 * 128 * 2);
    unsigned short* Rwt   = (unsigned short*)alloc((size_t)128 * 128 * 2);
    float* h_l   = (float*)alloc((size_t)N * 4 * 4);
    float* h_r   = (float*)alloc((size_t)N * 4 * 4);
    float* h_e_t = (float*)alloc((size_t)T * NH * 4);
    int* bucket_cursor = (int*)alloc(2048 * 4);
    unsigned* ebuf = (unsigned*)alloc((size_t)(NB + 1) * BCAP * 4);

    int nFill = (E + 8191) / 8192;
    int nGemm = (N + 63) / 64;

    hipLaunchKernelGGL(k_prep, dim3(64 + T), dim3(256), 0, stream,
                       W, res_w, Wt, Rwt, bucket_cursor,
                       edge_emb, W_r, a_e, h_e_t);
    hipLaunchKernelGGL(k_gemm_fill, dim3(nFill + nGemm), dim3(256), 0, stream,
                       h, Wt, Rwt, res_b, a_l, a_r, embBf, resBf, h_l, h_r, N,
                       row, col, etype, bucket_cursor, ebuf, E, NB, nFill);
    hipLaunchKernelGGL(k_sort_aggregate, dim3(NB), dim3(512), 0, stream,
                       ebuf, bucket_cursor, h_l, h_e_t, h_r, embBf, resBf, out, N);
}

// Round 19
// 81.195 us; speedup vs baseline: 1.1283x; 1.0661x over previous
//
#include <hip/hip_runtime.h>
#include <math.h>

#define NH 4
#define EDIM 32
#define NEG_SLOPE 0.2f
#define BSH 5                  // bucket = col>>5 (32 nodes per bucket)
#define BCAP 1024              // fixed capacity per bucket segment (mean ~512)

typedef __attribute__((ext_vector_type(8))) short short8;
typedef __attribute__((ext_vector_type(4))) float f32x4;
typedef __attribute__((ext_vector_type(2))) float f32x2;

__device__ __forceinline__ unsigned short f2bf(float f) {
    unsigned int x = __builtin_bit_cast(unsigned int, f);
    unsigned int r = (x + 0x7fffu + ((x >> 16) & 1u)) >> 16;
    return (unsigned short)r;
}
__device__ __forceinline__ float bf2f(unsigned short u) {
    unsigned int x = ((unsigned int)u) << 16;
    return __builtin_bit_cast(float, x);
}

// ---------------------------------------------------------------------------
// Prep: blocks [0,64): weight transpose+bf16 + zero bucket cursors.
//       blocks [64,64+T): h_e_t for one edge type each.
__global__ __launch_bounds__(256) void k_prep(
    const float* __restrict__ W, const float* __restrict__ Rw,
    unsigned short* __restrict__ Wt, unsigned short* __restrict__ Rwt,
    int* __restrict__ bucket_cursor,
    const float* __restrict__ edge_emb, const float* __restrict__ W_r,
    const float* __restrict__ a_e, float* __restrict__ h_e_t)
{
    int tid = threadIdx.x;
    if (blockIdx.x < 64) {
        int idx = blockIdx.x * 256 + tid;       // 0..16383
        int n = idx >> 7, k = idx & 127;
        Wt[n * 128 + k]  = f2bf(W[k * 128 + n]);
        Rwt[n * 128 + k] = f2bf(Rw[k * 128 + n]);
        if (idx < 2048) bucket_cursor[idx] = 0;
        return;
    }
    int t = blockIdx.x - 64;
    if (tid < 128) {
        int rem = tid;                          // h*32+k
        float v = 0.f;
#pragma unroll
        for (int e = 0; e < EDIM; ++e)
            v += edge_emb[t * EDIM + e] * W_r[(size_t)(t * EDIM + e) * 128 + rem];
        v *= a_e[rem];
#pragma unroll
        for (int off = 16; off >= 1; off >>= 1)
            v += __shfl_xor(v, off);
        if ((rem & 31) == 0) h_e_t[t * NH + (rem >> 5)] = v;
    }
}

// ---------------------------------------------------------------------------
// Merged: blocks [0,nFill) = bucket scatter (8192 edges each);
//         blocks [nFill,..) = MFMA GEMM with 32KB LDS (A + half-B staging).
__global__ __launch_bounds__(256) void k_gemm_fill(
    const float* __restrict__ A, const unsigned short* __restrict__ Wt,
    const unsigned short* __restrict__ Rwt, const float* __restrict__ Rb,
    const float* __restrict__ a_l, const float* __restrict__ a_r,
    unsigned short* __restrict__ EmbBf, unsigned short* __restrict__ ResBf,
    float* __restrict__ h_l, float* __restrict__ h_r, int M,
    const int* __restrict__ row, const int* __restrict__ col,
    const int* __restrict__ etype, int* __restrict__ bucket_cursor,
    unsigned* __restrict__ ebuf, int E, int NB, int nFill)
{
    __shared__ char lds[32768];                 // [0,16K) A ; [16K,32K) B-half
    int tid = threadIdx.x;

    if ((int)blockIdx.x < nFill) {
        // ---- single-pass bucket scatter into fixed-capacity segments ----
        int* bins = (int*)lds;
        int* base = bins + 2048;
        for (int i = tid; i < NB; i += 256) bins[i] = 0;
        __syncthreads();
        int lo = blockIdx.x * 8192;
        int ccol[32];
#pragma unroll
        for (int u = 0; u < 32; ++u) {
            int i = lo + tid + u * 256;
            int c = (i < E) ? col[i] : -1;
            ccol[u] = c;
            if (c >= 0) atomicAdd(&bins[c >> BSH], 1);
        }
        __syncthreads();
        for (int i = tid; i < NB; i += 256) {
            int c = bins[i];
            base[i] = c ? atomicAdd(&bucket_cursor[i], c) : 0;
            bins[i] = 0;                        // reuse as local cursor
        }
        __syncthreads();
#pragma unroll
        for (int u = 0; u < 32; ++u) {
            int i = lo + tid + u * 256;
            int c = ccol[u];
            if (c >= 0) {
                int bk = c >> BSH;
                int p = bk * BCAP + base[bk] + atomicAdd(&bins[bk], 1);
                ebuf[p] = (unsigned)row[i] | ((unsigned)etype[i] << 16)
                        | ((unsigned)(c & 31) << 24);
            }
        }
        return;
    }

    // ---- MFMA GEMM ----
    int m0 = ((int)blockIdx.x - nFill) * 64;
#pragma unroll
    for (int i = 0; i < 4; ++i) {
        int c = tid + 256 * i;                  // 0..1023
        int r = c >> 4, kc = c & 15;
        int grow = m0 + r;
        float4 v0 = make_float4(0.f, 0.f, 0.f, 0.f), v1 = v0;
        if (grow < M) {
            v0 = *(const float4*)&A[(size_t)grow * 128 + kc * 8];
            v1 = *(const float4*)&A[(size_t)grow * 128 + kc * 8 + 4];
        }
        union { unsigned short u[8]; uint4 v; } p;
        p.u[0] = f2bf(v0.x); p.u[1] = f2bf(v0.y); p.u[2] = f2bf(v0.z); p.u[3] = f2bf(v0.w);
        p.u[4] = f2bf(v1.x); p.u[5] = f2bf(v1.y); p.u[6] = f2bf(v1.z); p.u[7] = f2bf(v1.w);
        int b = (r * 256 + kc * 16) ^ ((r & 7) << 4);
        *(uint4*)&lds[b] = p.v;
    }

    int w = tid >> 6, lane = tid & 63;
    int g = lane >> 4, l15 = lane & 15;
    int lrow = w * 16 + l15;

    auto stageB = [&](const unsigned short* src) {
#pragma unroll
        for (int i = 0; i < 4; ++i) {
            int c = tid + 256 * i;              // 0..1023
            int n2 = c >> 4, kc = c & 15;
            uint4 v = *(const uint4*)&src[n2 * 128 + kc * 8];
            int b = 16384 + ((n2 * 256 + kc * 16) ^ ((n2 & 7) << 4));
            *(uint4*)&lds[b] = v;
        }
    };
    auto computeHalf = [&](f32x4* accp, const short8* a) {
#pragma unroll
        for (int f = 0; f < 4; ++f) {
            int n2 = f * 16 + l15;
            int nsw = (n2 & 7) << 4;
#pragma unroll
            for (int s = 0; s < 4; ++s) {
                short8 b = *(const short8*)&lds[16384 + ((n2 * 256 + s * 64 + g * 16) ^ nsw)];
                accp[f] = __builtin_amdgcn_mfma_f32_16x16x32_bf16(a[s], b, accp[f], 0, 0, 0);
            }
        }
    };

    stageB(Wt);
    __syncthreads();

    short8 a[4];
#pragma unroll
    for (int s = 0; s < 4; ++s)
        a[s] = *(const short8*)&lds[(lrow * 256 + s * 64 + g * 16) ^ ((lrow & 7) << 4)];

    f32x4 acc[8];
#pragma unroll
    for (int f = 0; f < 8; ++f) acc[f] = (f32x4){0.f, 0.f, 0.f, 0.f};

    computeHalf(&acc[0], a);                    // cols 0..63
    __syncthreads();
    stageB(Wt + 64 * 128);
    __syncthreads();
    computeHalf(&acc[4], a);                    // cols 64..127

#pragma unroll
    for (int f = 0; f < 8; ++f) {
        int col2 = f * 16 + l15;
#pragma unroll
        for (int reg = 0; reg < 4; ++reg) {
            int grow = m0 + w * 16 + g * 4 + reg;
            if (grow < M) EmbBf[(size_t)grow * 128 + col2] = f2bf(acc[f][reg]);
        }
    }
    {
        float alv[8], arv[8];
#pragma unroll
        for (int f = 0; f < 8; ++f) {
            alv[f] = a_l[f * 16 + l15];
            arv[f] = a_r[f * 16 + l15];
        }
#pragma unroll
        for (int reg = 0; reg < 4; ++reg) {
            float4 hl4, hr4;
#pragma unroll
            for (int hh = 0; hh < 4; ++hh) {
                float pl = alv[2 * hh] * acc[2 * hh][reg] + alv[2 * hh + 1] * acc[2 * hh + 1][reg];
                float pr = arv[2 * hh] * acc[2 * hh][reg] + arv[2 * hh + 1] * acc[2 * hh + 1][reg];
#pragma unroll
                for (int off = 8; off >= 1; off >>= 1) {
                    pl += __shfl_xor(pl, off);
                    pr += __shfl_xor(pr, off);
                }
                (&hl4.x)[hh] = pl;
                (&hr4.x)[hh] = pr;
            }
            int grow = m0 + w * 16 + g * 4 + reg;
            if (l15 == 0 && grow < M) {
                *(float4*)&h_l[(size_t)grow * 4] = hl4;
                *(float4*)&h_r[(size_t)grow * 4] = hr4;
            }
        }
    }

    // ---- res pass ----
    __syncthreads();
    stageB(Rwt);
    __syncthreads();
#pragma unroll
    for (int f = 0; f < 8; ++f) acc[f] = (f32x4){0.f, 0.f, 0.f, 0.f};
    computeHalf(&acc[0], a);
    __syncthreads();
    stageB(Rwt + 64 * 128);
    __syncthreads();
    computeHalf(&acc[4], a);

#pragma unroll
    for (int f = 0; f < 8; ++f) {
        int col2 = f * 16 + l15;
        float bias = Rb[col2];
#pragma unroll
        for (int reg = 0; reg < 4; ++reg) {
            int grow = m0 + w * 16 + g * 4 + reg;
            if (grow < M) ResBf[(size_t)grow * 128 + col2] = f2bf(acc[f][reg] + bias);
        }
    }
}

// ---------------------------------------------------------------------------
// Fused within-bucket sort + aggregate.  512 threads (8 waves) per 32-node
// bucket: 4 sequential node-iterations per wave.  Padded pair-edge dwordx2
// gather (zero-padded LDS alpha slots; no clamp in the inner loop).
__global__ __launch_bounds__(512) void k_sort_aggregate(
    const unsigned* __restrict__ ebuf, const int* __restrict__ bucket_cursor,
    const float* __restrict__ h_l, const float* __restrict__ h_e_t,
    const float* __restrict__ h_r, const unsigned short* __restrict__ embBf,
    const unsigned short* __restrict__ resBf, float* __restrict__ out, int N)
{
    __shared__ int sedge[BCAP];
    __shared__ int cnt[32];
    __shared__ int scn[33];
    __shared__ char shalpha[8 * 1536];

    int b = blockIdx.x;
    int tid = threadIdx.x;
    int seg = b * BCAP;
    int m = bucket_cursor[b];                   // relative count

    if (tid < 32) cnt[tid] = 0;
    __syncthreads();
    for (int i = tid; i < m; i += 512)
        atomicAdd(&cnt[(ebuf[seg + i] >> 24) & 31], 1);
    __syncthreads();
    if (tid < 32) {
        int v = cnt[tid];
        int s = v;
#pragma unroll
        for (int off = 1; off < 32; off <<= 1) {
            int u2 = __shfl_up(s, off);
            if (tid >= off) s += u2;
        }
        scn[tid + 1] = s;
        if (tid == 0) scn[0] = 0;
        cnt[tid] = s - v;                       // exclusive; reuse as cursor
    }
    __syncthreads();
    for (int i = tid; i < m; i += 512) {
        unsigned e = ebuf[seg + i];
        int p = atomicAdd(&cnt[(e >> 24) & 31], 1);
        sedge[p] = (int)(e & 0x00FFFFFFu);
    }
    __syncthreads();

    int w = tid >> 6, lane = tid & 63;
    int myh = lane >> 4;                        // parking/fallback head
    int l31 = lane & 31;
    int sel = lane >> 5;                        // which edge of the pair
    int hq = l31 >> 3;                          // gather head (elements l31*4..+3)
    int loff = l31 * 8;
    char* wb = &shalpha[w * 1536];
    const char* ab2 = wb + 256 + hq * 260;
    const char* embByte = (const char*)embBf;

    for (int it = 0; it < 4; ++it) {
        int nd = it * 8 + w;
        int n = b * 32 + nd;
        if (n >= N) break;
        int st0 = scn[nd];
        int deg = scn[nd + 1] - st0;
        float4 hrv = *(const float4*)&h_r[(size_t)n * 4];

        if (deg <= 64) {
            bool act = lane < deg;
            float p0 = 0.f, p1 = 0.f, p2 = 0.f, p3 = 0.f;
            int roval = 0;
            if (act) {
                int pk = sedge[st0 + lane];
                roval = (pk & 0xffff) << 8;     // emb byte offset
                float4 hl = *(const float4*)&h_l[(size_t)(pk & 0xffff) * 4];
                float4 he = *(const float4*)&h_e_t[(size_t)(pk >> 16) * 4];
                float sc0 = hl.x + he.x + hrv.x; sc0 = sc0 > 0.f ? sc0 : NEG_SLOPE * sc0;
                float sc1 = hl.y + he.y + hrv.y; sc1 = sc1 > 0.f ? sc1 : NEG_SLOPE * sc1;
                float sc2 = hl.z + he.z + hrv.z; sc2 = sc2 > 0.f ? sc2 : NEG_SLOPE * sc2;
                float sc3 = hl.w + he.w + hrv.w; sc3 = sc3 > 0.f ? sc3 : NEG_SLOPE * sc3;
                p0 = __expf(sc0); p1 = __expf(sc1);
                p2 = __expf(sc2); p3 = __expf(sc3);
            }
            // park ALL lanes (zero padding -> no clamp in gather loop)
            *(int*)(wb + lane * 4) = roval;
            *(float*)(wb + 256 + 0 * 260 + lane * 4) = p0;
            *(float*)(wb + 256 + 1 * 260 + lane * 4) = p1;
            *(float*)(wb + 256 + 2 * 260 + lane * 4) = p2;
            *(float*)(wb + 256 + 3 * 260 + lane * 4) = p3;

            float d0 = p0, d1 = p1, d2 = p2, d3 = p3;
#pragma unroll
            for (int off = 32; off >= 1; off >>= 1) {
                d0 += __shfl_xor(d0, off); d1 += __shfl_xor(d1, off);
                d2 += __shfl_xor(d2, off); d3 += __shfl_xor(d3, off);
            }
            float den = hq == 0 ? d0 : hq == 1 ? d1 : hq == 2 ? d2 : d3;
            float inv = (deg > 0) ? __builtin_amdgcn_rcpf(den) : 0.f;

            f32x4 acc4 = (f32x4){0.f, 0.f, 0.f, 0.f};
            for (int q = 0; q < deg; q += 8) {  // 4 pairs = 8 edges; tail = zeros
                int ro[4]; float aq[4];
#pragma unroll
                for (int u = 0; u < 4; ++u) {
                    int qe = q + 2 * u + sel;
                    ro[u] = *(const int*)(wb + qe * 4);
                    aq[u] = *(const float*)(ab2 + qe * 4);
                }
                uint2 ev[4];
#pragma unroll
                for (int u = 0; u < 4; ++u)
                    ev[u] = *(const uint2*)(embByte + (size_t)(unsigned)(ro[u] + loff));
#pragma unroll
                for (int u = 0; u < 4; ++u) {
                    f32x4 ef;
                    ef.x = __builtin_bit_cast(float, ev[u].x << 16);
                    ef.y = __builtin_bit_cast(float, ev[u].x & 0xffff0000u);
                    ef.z = __builtin_bit_cast(float, ev[u].y << 16);
                    ef.w = __builtin_bit_cast(float, ev[u].y & 0xffff0000u);
                    acc4 = __builtin_elementwise_fma(
                        ef, (f32x4){aq[u], aq[u], aq[u], aq[u]}, acc4);
                }
            }
            acc4.x += __shfl_xor(acc4.x, 32);
            acc4.y += __shfl_xor(acc4.y, 32);
            acc4.z += __shfl_xor(acc4.z, 32);
            acc4.w += __shfl_xor(acc4.w, 32);
            float vlo = sel ? acc4.z : acc4.x;
            float vhi = sel ? acc4.w : acc4.y;

            int j0 = l31 * 4 + sel * 2;         // flat j = h*32+d
            int h0 = j0 >> 5, dd = j0 & 31;
            size_t ob = (size_t)n * 128;
            float o0 = vlo * inv + bf2f(resBf[ob + dd * 4 + h0]);
            float o1 = vhi * inv + bf2f(resBf[ob + (dd + 1) * 4 + h0]);
            out[ob + dd * 4 + h0] = o0 > 0.f ? o0 : expm1f(o0);
            out[ob + (dd + 1) * 4 + h0] = o1 > 0.f ? o1 : expm1f(o1);
        } else {
            // ---- chunked fallback (deg>64, rare): 2-elem/lane layout ----
            f32x2 acc2 = (f32x2){0.f, 0.f};
            float d0 = 0.f, d1 = 0.f, d2 = 0.f, d3 = 0.f;
            for (int base2 = 0; base2 < deg; base2 += 64) {
                int el = base2 + lane;
                if (el < deg) {
                    int pk = sedge[st0 + el];
                    float4 hl = *(const float4*)&h_l[(size_t)(pk & 0xffff) * 4];
                    float4 he = *(const float4*)&h_e_t[(size_t)(pk >> 16) * 4];
                    float sc0 = hl.x + he.x + hrv.x; sc0 = sc0 > 0.f ? sc0 : NEG_SLOPE * sc0;
                    float sc1 = hl.y + he.y + hrv.y; sc1 = sc1 > 0.f ? sc1 : NEG_SLOPE * sc1;
                    float sc2 = hl.z + he.z + hrv.z; sc2 = sc2 > 0.f ? sc2 : NEG_SLOPE * sc2;
                    float sc3 = hl.w + he.w + hrv.w; sc3 = sc3 > 0.f ? sc3 : NEG_SLOPE * sc3;
                    d0 += __expf(sc0); d1 += __expf(sc1);
                    d2 += __expf(sc2); d3 += __expf(sc3);
                }
            }
#pragma unroll
            for (int off = 32; off >= 1; off >>= 1) {
                d0 += __shfl_xor(d0, off); d1 += __shfl_xor(d1, off);
                d2 += __shfl_xor(d2, off); d3 += __shfl_xor(d3, off);
            }
            float den = myh == 0 ? d0 : myh == 1 ? d1 : myh == 2 ? d2 : d3;
            float inv = __builtin_amdgcn_rcpf(den);
            for (int base2 = 0; base2 < deg; base2 += 64) {
                int el = base2 + lane;
                float p0 = 0.f, p1 = 0.f, p2 = 0.f, p3 = 0.f;
                int r = 0;
                if (el < deg) {
                    int pk = sedge[st0 + el];
                    r = pk & 0xffff;
                    float4 hl = *(const float4*)&h_l[(size_t)r * 4];
                    float4 he = *(const float4*)&h_e_t[(size_t)(pk >> 16) * 4];
                    float sc0 = hl.x + he.x + hrv.x; sc0 = sc0 > 0.f ? sc0 : NEG_SLOPE * sc0;
                    float sc1 = hl.y + he.y + hrv.y; sc1 = sc1 > 0.f ? sc1 : NEG_SLOPE * sc1;
                    float sc2 = hl.z + he.z + hrv.z; sc2 = sc2 > 0.f ? sc2 : NEG_SLOPE * sc2;
                    float sc3 = hl.w + he.w + hrv.w; sc3 = sc3 > 0.f ? sc3 : NEG_SLOPE * sc3;
                    p0 = __expf(sc0); p1 = __expf(sc1);
                    p2 = __expf(sc2); p3 = __expf(sc3);
                }
                int cmax = (deg - base2 < 64) ? (deg - base2) : 64;
                for (int qq = 0; qq < cmax; ++qq) {
                    int rq = __shfl(r, qq);
                    float a0 = __shfl(p0, qq), a1 = __shfl(p1, qq);
                    float a2 = __shfl(p2, qq), a3 = __shfl(p3, qq);
                    float aqv = myh == 0 ? a0 : myh == 1 ? a1 : myh == 2 ? a2 : a3;
                    unsigned int ev = *(const unsigned int*)&embBf[(size_t)rq * 128 + lane * 2];
                    f32x2 ef;
                    ef.x = __builtin_bit_cast(float, ev << 16);
                    ef.y = __builtin_bit_cast(float, ev & 0xffff0000u);
                    acc2 = __builtin_elementwise_fma(ef, (f32x2){aqv, aqv}, acc2);
                }
            }
            int j0 = lane * 2;
            int h0 = j0 >> 5, dd0 = j0 & 31;
            size_t ob = (size_t)n * 128;
            float o0 = acc2.x * inv + bf2f(resBf[ob + dd0 * 4 + h0]);
            float o1 = acc2.y * inv + bf2f(resBf[ob + (dd0 + 1) * 4 + h0]);
            out[ob + dd0 * 4 + h0] = o0 > 0.f ? o0 : expm1f(o0);
            out[ob + (dd0 + 1) * 4 + h0] = o1 > 0.f ? o1 : expm1f(o1);
        }
    }
}

// ---------------------------------------------------------------------------
extern "C" void kernel_launch(void* const* d_in, const int* in_sizes, int n_in,
                              void* d_out, int out_size, void* d_ws, size_t ws_size,
                              hipStream_t stream)
{
    const float* h        = (const float*)d_in[0];
    const float* W        = (const float*)d_in[1];
    const float* edge_emb = (const float*)d_in[2];
    const float* W_r      = (const float*)d_in[3];
    const float* a_l      = (const float*)d_in[4];
    const float* a_r      = (const float*)d_in[5];
    const float* a_e      = (const float*)d_in[6];
    const float* res_w    = (const float*)d_in[7];
    const float* res_b    = (const float*)d_in[8];
    const int*   row      = (const int*)d_in[9];
    const int*   col      = (const int*)d_in[10];
    const int*   etype    = (const int*)d_in[11];
    float* out = (float*)d_out;

    int N = in_sizes[0] / 128;
    int E = in_sizes[9];
    int T = in_sizes[2] / EDIM;
    int NB = (N + 31) >> BSH;                   // 32-node buckets

    char* ws = (char*)d_ws;
    size_t off = 0;
    auto alloc = [&](size_t bytes) -> char* {
        char* p = ws + off;
        off = (off + bytes + 255) & ~(size_t)255;
        return p;
    };
    unsigned short* embBf = (unsigned short*)alloc((size_t)N * 128 * 2);
    unsigned short* resBf = (unsigned short*)alloc((size_t)N * 128 * 2);
    unsigned short* Wt    = (unsigned short*)alloc((size_t)128 * 128 * 2);
    unsigned short* Rwt   = (unsigned short*)alloc((size_t)128 * 128 * 2);
    float* h_l   = (float*)alloc((size_t)N * 4 * 4);
    float* h_r   = (float*)alloc((size_t)N * 4 * 4);
    float* h_e_t = (float*)alloc((size_t)T * NH * 4);
    int* bucket_cursor = (int*)alloc(2048 * 4);
    unsigned* ebuf = (unsigned*)alloc((size_t)(NB + 1) * BCAP * 4);

    int nFill = (E + 8191) / 8192;
    int nGemm = (N + 63) / 64;

    hipLaunchKernelGGL(k_prep, dim3(64 + T), dim3(256), 0, stream,
                       W, res_w, Wt, Rwt, bucket_cursor,
                       edge_emb, W_r, a_e, h_e_t);
    hipLaunchKernelGGL(k_gemm_fill, dim3(nFill + nGemm), dim3(256), 0, stream,
                       h, Wt, Rwt, res_b, a_l, a_r, embBf, resBf, h_l, h_r, N,
                       row, col, etype, bucket_cursor, ebuf, E, NB, nFill);
    hipLaunchKernelGGL(k_sort_aggregate, dim3(NB), dim3(512), 0, stream,
                       ebuf, bucket_cursor, h_l, h_e_t, h_r, embBf, resBf, out, N);
}